// Round 1
// baseline (1059.256 us; speedup 1.0000x reference)
//
#include <hip/hip_runtime.h>

// deepSNN forward, layer_idx=3 path, fp32 exact.
// x:(20,6,160,160) w1:(30,6,4,4) w2:(250,30,3,3) w3:(200,250,3,3)
// pipeline: pad2->conv1->fire(1)->pool2x2 -> pad2->conv2->fire(1)->pool3x3
//           -> pad2->conv3->fire(25) -> out = [spk | pot] (2 x 20*200*29*29 fp32)

#define OUT_HALF 3364000  // 20*200*29*29

// ---------------- one-time weight transpose: w[oc][ck] -> wt[ck][oc] --------
__global__ void k_transpose(const float* __restrict__ w, float* __restrict__ wt,
                            int OC, int CK) {
    int idx = blockIdx.x * 256 + threadIdx.x;
    if (idx < OC * CK) {
        int oc = idx / CK, ck = idx % CK;
        wt[ck * OC + oc] = w[idx];
    }
}

// ---------------- conv1(4x4) + fire(1.0) + pool2x2 -> pool1 u8 (20,30,80,80)
// block: (t, 10 row-tiles of 8 pool rows, 5 col-tiles of 16 pool cols), 256 thr
__global__ __launch_bounds__(256) void k_conv1(const float* __restrict__ x,
                                               const float* __restrict__ w1,
                                               unsigned char* __restrict__ pool1) {
    __shared__ float in_lds[6 * 19 * 35];  // 3990 floats
    __shared__ float w_lds[30 * 96];       // 2880 floats

    int b = blockIdx.x;
    int colt = b % 5;  b /= 5;
    int rowt = b % 10; b /= 10;
    int t = b;
    int ph0 = rowt * 8, pw0 = colt * 16;
    int i0 = 2 * ph0, j0 = 2 * pw0;  // padded-164 coords of tile conv origin
    int tid = threadIdx.x;

    for (int idx = tid; idx < 6 * 19 * 35; idx += 256) {
        int c = idx / 665;
        int rem = idx % 665;
        int r = rem / 35, col = rem % 35;
        int gr = i0 + r - 2, gc = j0 + col - 2;
        float v = 0.f;
        if ((unsigned)gr < 160u && (unsigned)gc < 160u)
            v = x[((t * 6 + c) * 160 + gr) * 160 + gc];
        in_lds[idx] = v;
    }
    for (int idx = tid; idx < 2880; idx += 256) w_lds[idx] = w1[idx];
    __syncthreads();

    int pw_l = tid & 15, ph_l = tid >> 4;
    int rb = 2 * ph_l, cb = 2 * pw_l;

    for (int occ = 0; occ < 5; ++occ) {  // 5 chunks of 6 output channels
        float acc[6][4];
#pragma unroll
        for (int o = 0; o < 6; ++o)
#pragma unroll
            for (int p = 0; p < 4; ++p) acc[o][p] = 0.f;

        for (int c = 0; c < 6; ++c) {
            float in[5][5];
#pragma unroll
            for (int r = 0; r < 5; ++r)
#pragma unroll
                for (int cc = 0; cc < 5; ++cc)
                    in[r][cc] = in_lds[c * 665 + (rb + r) * 35 + cb + cc];
#pragma unroll
            for (int o = 0; o < 6; ++o) {
                const float* wp = &w_lds[(occ * 6 + o) * 96 + c * 16];
#pragma unroll
                for (int kh = 0; kh < 4; ++kh)
#pragma unroll
                    for (int kw = 0; kw < 4; ++kw) {
                        float w = wp[kh * 4 + kw];
                        acc[o][0] += in[kh][kw] * w;
                        acc[o][1] += in[kh][kw + 1] * w;
                        acc[o][2] += in[kh + 1][kw] * w;
                        acc[o][3] += in[kh + 1][kw + 1] * w;
                    }
            }
        }
#pragma unroll
        for (int o = 0; o < 6; ++o) {
            bool s = acc[o][0] > 1.f || acc[o][1] > 1.f ||
                     acc[o][2] > 1.f || acc[o][3] > 1.f;
            pool1[((t * 30 + occ * 6 + o) * 80 + ph0 + ph_l) * 80 + pw0 + pw_l] =
                s ? (unsigned char)1 : (unsigned char)0;
        }
    }
}

// ---------------- conv2(3x3) + fire(1.0) + pool3x3 -> pool2 u8 (20,250,27,27)
// block: (t, 4 oc-groups of 64, 7 pw-groups of 4, 27 ph), 256 thr = 64oc x 4pw
// thread: 3x3 conv patch (= 1 pool output) for one oc. c-chunked LDS (2x15).
__global__ __launch_bounds__(256) void k_conv2(const unsigned char* __restrict__ pool1,
                                               const float* __restrict__ w2t,
                                               unsigned char* __restrict__ pool2) {
    __shared__ float w_lds[15 * 9 * 64];   // 8640 floats, [ck_local][ocl]
    __shared__ float in_lds[15 * 5 * 14];  // 1050 floats, [cl][r][col]

    int b = blockIdx.x;
    int ph = b % 27;  b /= 27;
    int pwg = b % 7;  b /= 7;
    int ocg = b % 4;  b /= 4;
    int t = b;
    int oc0 = ocg * 64, pw0 = pwg * 4;
    int tid = threadIdx.x;
    int ocl = tid & 63, pwl = tid >> 6;  // wave-uniform pwl -> input broadcast
    int i0 = 3 * ph, j0 = 3 * pw0;       // padded-84 coords
    int cbase = 3 * pwl;

    float acc[3][3];
#pragma unroll
    for (int i = 0; i < 3; ++i)
#pragma unroll
        for (int j = 0; j < 3; ++j) acc[i][j] = 0.f;

    for (int ch = 0; ch < 2; ++ch) {  // channel chunks of 15
        // stage weights for this chunk: w_lds[ckl*64 + ocl]
        for (int idx = tid; idx < 15 * 9 * 64; idx += 256) {
            int o = idx & 63, ckl = idx >> 6;  // ckl in [0,135)
            int oc = oc0 + o;
            int ckg = ch * 135 + ckl;
            w_lds[idx] = (oc < 250) ? w2t[ckg * 250 + oc] : 0.f;
        }
        // stage input rows i0..i0+4, cols j0..j0+13 for 15 channels
        for (int idx = tid; idx < 15 * 5 * 14; idx += 256) {
            int cl = idx / 70;
            int rem = idx % 70;
            int r = rem / 14, col = rem % 14;
            int gr = i0 + r - 2, gc = j0 + col - 2;
            float v = 0.f;
            if ((unsigned)gr < 80u && (unsigned)gc < 80u)
                v = (float)pool1[((t * 30 + ch * 15 + cl) * 80 + gr) * 80 + gc];
            in_lds[idx] = v;
        }
        __syncthreads();

        for (int cl = 0; cl < 15; ++cl) {
            float in[5][5];
#pragma unroll
            for (int r = 0; r < 5; ++r)
#pragma unroll
                for (int j = 0; j < 5; ++j)
                    in[r][j] = in_lds[cl * 70 + r * 14 + cbase + j];
            const float* wp = &w_lds[cl * 576 + ocl];
#pragma unroll
            for (int k = 0; k < 9; ++k) {
                float w = wp[k * 64];
                int kh = k / 3, kw = k % 3;
#pragma unroll
                for (int i = 0; i < 3; ++i)
#pragma unroll
                    for (int j = 0; j < 3; ++j)
                        acc[i][j] += in[i + kh][j + kw] * w;
            }
        }
        __syncthreads();
    }

    bool s = false;
#pragma unroll
    for (int i = 0; i < 3; ++i)
#pragma unroll
        for (int j = 0; j < 3; ++j) s = s || (acc[i][j] > 1.f);

    int oc = oc0 + ocl, pw = pw0 + pwl;
    if (oc < 250 && pw < 27)
        pool2[((t * 250 + oc) * 27 + ph) * 27 + pw] = s ? (unsigned char)1
                                                        : (unsigned char)0;
}

// ---------------- conv3(3x3) + fire(25.0) -> out [spk|pot] (20,200,29,29) x2
// block: (t, 5 oc-groups of 40, 15 row-pairs), 320 thr = 40oc x 8 col-tiles(4)
// thread: 2x4 output patch for one oc. c-chunked LDS (10x25).
__global__ __launch_bounds__(320) void k_conv3(const unsigned char* __restrict__ pool2,
                                               const float* __restrict__ w3t,
                                               float* __restrict__ out) {
    __shared__ float w_lds[25 * 9 * 40];   // 9000 floats, [ck_local][ocl]
    __shared__ float in_lds[25 * 4 * 34];  // 3400 floats, [cl][r][col]

    int b = blockIdx.x;
    int rb = b % 15;  b /= 15;
    int ocg = b % 5;  b /= 5;
    int t = b;
    int oc0 = ocg * 40;
    int r0 = 2 * rb;  // output rows r0, r0+1
    int tid = threadIdx.x;
    int ocl = tid % 40, ct = tid / 40;  // ct in [0,8)

    float acc[2][4];
#pragma unroll
    for (int i = 0; i < 2; ++i)
#pragma unroll
        for (int j = 0; j < 4; ++j) acc[i][j] = 0.f;

    for (int chn = 0; chn < 10; ++chn) {  // channel chunks of 25
        int cc0 = chn * 25;
        // weights: w_lds[ck*40 + ocl], ck = cl*9+k in [0,225)
        for (int idx = tid; idx < 25 * 9 * 40; idx += 320) {
            int o = idx % 40, ck = idx / 40;
            int ckg = cc0 * 9 + ck;
            w_lds[idx] = w3t[ckg * 200 + oc0 + o];  // oc0+o < 200 always
        }
        // inputs: padded-31 rows r0..r0+3, cols 0..33 (zero-padded past 30)
        for (int idx = tid; idx < 25 * 4 * 34; idx += 320) {
            int col = idx % 34;
            int rem = idx / 34;
            int r = rem & 3, cl = rem >> 2;
            int gr = r0 + r - 2, gc = col - 2;
            float v = 0.f;
            if ((unsigned)gr < 27u && (unsigned)gc < 27u)
                v = (float)pool2[((t * 250 + cc0 + cl) * 27 + gr) * 27 + gc];
            in_lds[idx] = v;
        }
        __syncthreads();

        for (int cl = 0; cl < 25; ++cl) {
            float in[4][6];
#pragma unroll
            for (int r = 0; r < 4; ++r)
#pragma unroll
                for (int j = 0; j < 6; ++j)
                    in[r][j] = in_lds[(cl * 4 + r) * 34 + ct * 4 + j];
            const float* wp = &w_lds[cl * 360 + ocl];
#pragma unroll
            for (int k = 0; k < 9; ++k) {
                float w = wp[k * 40];
                int kh = k / 3, kw = k % 3;
#pragma unroll
                for (int i = 0; i < 2; ++i)
#pragma unroll
                    for (int j = 0; j < 4; ++j)
                        acc[i][j] += in[i + kh][j + kw] * w;
            }
        }
        __syncthreads();
    }

    int oc = oc0 + ocl;  // always < 200
#pragma unroll
    for (int i = 0; i < 2; ++i) {
        int r = r0 + i;
        if (r < 29) {
#pragma unroll
            for (int j = 0; j < 4; ++j) {
                int col = ct * 4 + j;
                if (col < 29) {
                    float pot = acc[i][j];
                    bool s = pot > 25.f;
                    size_t base = ((size_t)((t * 200 + oc) * 29 + r)) * 29 + col;
                    out[base] = s ? 1.f : 0.f;
                    out[OUT_HALF + base] = s ? pot : 0.f;
                }
            }
        }
    }
}

extern "C" void kernel_launch(void* const* d_in, const int* in_sizes, int n_in,
                              void* d_out, int out_size, void* d_ws, size_t ws_size,
                              hipStream_t stream) {
    const float* x  = (const float*)d_in[0];
    const float* w1 = (const float*)d_in[1];
    const float* w2 = (const float*)d_in[2];
    const float* w3 = (const float*)d_in[3];
    float* out = (float*)d_out;

    // workspace layout (bytes):
    //   pool1 u8 : [0, 3,840,000)            20*30*80*80
    //   pool2 u8 : [3,840,000, 7,485,000)    20*250*27*27
    //   w2t  f32 : [7,485,056, +270,000)     270x250
    //   w3t  f32 : [7,755,264, +1,800,000)   2250x200
    unsigned char* pool1 = (unsigned char*)d_ws;
    unsigned char* pool2 = pool1 + 3840000;
    float* w2t = (float*)((char*)d_ws + 7485056);
    float* w3t = (float*)((char*)d_ws + 7755264);

    k_transpose<<<(250 * 270 + 255) / 256, 256, 0, stream>>>(w2, w2t, 250, 270);
    k_transpose<<<(200 * 2250 + 255) / 256, 256, 0, stream>>>(w3, w3t, 200, 2250);
    k_conv1<<<20 * 10 * 5, 256, 0, stream>>>(x, w1, pool1);
    k_conv2<<<20 * 4 * 7 * 27, 256, 0, stream>>>(pool1, w2t, pool2);
    k_conv3<<<20 * 5 * 15, 320, 0, stream>>>(pool2, w3t, out);
}

// Round 2
// 856.490 us; speedup vs baseline: 1.2367x; 1.2367x over previous
//
#include <hip/hip_runtime.h>

// deepSNN forward, layer_idx=3 path, fp32 exact, sparsity-aware.
// x:(20,6,160,160) w1:(30,6,4,4) w2:(250,30,3,3) w3:(200,250,3,3)
// pipeline: pad2->conv1->fire(1)->pool2x2 -> pad2->conv2->fire(1)->pool3x3
//           -> pad2->conv3->fire(25) -> out = [spk | pot] (2 x 20*200*29*29 fp32)
// Spikes are near-empty (thresholds are many sigma above pot distributions), so
// conv2/conv3 blocks early-out via per-tile spike flags. Early-out is EXACT:
// zero receptive field -> pot = 0 -> (pot > thr) false -> spk = pot_out = 0.

#define OUT_HALF 3364000  // 20*200*29*29

// ---------------- one-time weight transpose: w[oc][ck] -> wt[ck][oc] --------
// Also zeroes `zp[0..zn)` (flags2) from block 0 — runs before conv kernels.
__global__ void k_transpose(const float* __restrict__ w, float* __restrict__ wt,
                            int OC, int CK, unsigned int* zp, int zn) {
    int idx = blockIdx.x * 256 + threadIdx.x;
    if (blockIdx.x == 0 && (int)threadIdx.x < zn) zp[threadIdx.x] = 0u;
    if (idx < OC * CK) {
        int oc = idx / CK, ck = idx % CK;
        wt[ck * OC + oc] = w[idx];
    }
}

// ---------------- conv1(4x4) + fire(1.0) + pool2x2 -> pool1 u8 (20,30,80,80)
// block: (t, 5 row-tiles of 16 pool rows, 5 col-tiles of 16 pool cols), 256 thr
// Also writes flags1[t][rowt][colt] = any spike in this 16x16x30 tile.
__global__ __launch_bounds__(256) void k_conv1(const float* __restrict__ x,
                                               const float* __restrict__ w1,
                                               unsigned char* __restrict__ pool1,
                                               unsigned int* __restrict__ flags1) {
    __shared__ float in_lds[6 * 35 * 35];  // 7350 floats
    __shared__ float w_lds[30 * 96];       // 2880 floats
    __shared__ int bf;

    int b = blockIdx.x;
    int colt = b % 5;  b /= 5;
    int rowt = b % 5;  b /= 5;
    int t = b;
    int ph0 = rowt * 16, pw0 = colt * 16;
    int i0 = 2 * ph0, j0 = 2 * pw0;  // padded-164 coords of tile conv origin
    int tid = threadIdx.x;
    if (tid == 0) bf = 0;

    for (int idx = tid; idx < 6 * 35 * 35; idx += 256) {
        int c = idx / 1225;
        int rem = idx % 1225;
        int r = rem / 35, col = rem % 35;
        int gr = i0 + r - 2, gc = j0 + col - 2;
        float v = 0.f;
        if ((unsigned)gr < 160u && (unsigned)gc < 160u)
            v = x[((t * 6 + c) * 160 + gr) * 160 + gc];
        in_lds[idx] = v;
    }
    for (int idx = tid; idx < 2880; idx += 256) w_lds[idx] = w1[idx];
    __syncthreads();

    int pw_l = tid & 15, ph_l = tid >> 4;  // 16x16 threads == 16x16 pool tile
    int rb = 2 * ph_l, cb = 2 * pw_l;
    bool any = false;

    for (int occ = 0; occ < 5; ++occ) {  // 5 chunks of 6 output channels
        float acc[6][4];
#pragma unroll
        for (int o = 0; o < 6; ++o)
#pragma unroll
            for (int p = 0; p < 4; ++p) acc[o][p] = 0.f;

        for (int c = 0; c < 6; ++c) {
            float in[5][5];
#pragma unroll
            for (int r = 0; r < 5; ++r)
#pragma unroll
                for (int cc = 0; cc < 5; ++cc)
                    in[r][cc] = in_lds[c * 1225 + (rb + r) * 35 + cb + cc];
#pragma unroll
            for (int o = 0; o < 6; ++o) {
                const float* wp = &w_lds[(occ * 6 + o) * 96 + c * 16];
#pragma unroll
                for (int kh = 0; kh < 4; ++kh)
#pragma unroll
                    for (int kw = 0; kw < 4; ++kw) {
                        float w = wp[kh * 4 + kw];
                        acc[o][0] += in[kh][kw] * w;
                        acc[o][1] += in[kh][kw + 1] * w;
                        acc[o][2] += in[kh + 1][kw] * w;
                        acc[o][3] += in[kh + 1][kw + 1] * w;
                    }
            }
        }
#pragma unroll
        for (int o = 0; o < 6; ++o) {
            bool s = acc[o][0] > 1.f || acc[o][1] > 1.f ||
                     acc[o][2] > 1.f || acc[o][3] > 1.f;
            any = any || s;
            pool1[((t * 30 + occ * 6 + o) * 80 + ph0 + ph_l) * 80 + pw0 + pw_l] =
                s ? (unsigned char)1 : (unsigned char)0;
        }
    }
    if (any) bf = 1;  // same-value LDS stores, race-safe
    __syncthreads();
    if (tid == 0) flags1[t * 25 + rowt * 5 + colt] = (unsigned int)bf;
}

// ---------------- conv2(3x3) + fire(1.0) + pool3x3 -> pool2 u8 (20,250,27,27)
// block: (t, 4 oc-groups of 64, 7 pw-groups of 4, 27 ph), 256 thr = 64oc x 4pw
// Early-out via flags1 (<=4 overlapping conv1 tiles). Sets flags2[t][ph] if
// any pool2 spike produced.
__global__ __launch_bounds__(256) void k_conv2(const unsigned char* __restrict__ pool1,
                                               const float* __restrict__ w2t,
                                               unsigned char* __restrict__ pool2,
                                               const unsigned int* __restrict__ flags1,
                                               unsigned int* __restrict__ flags2) {
    __shared__ float w_lds[15 * 9 * 64];   // 8640 floats, [ck_local][ocl]
    __shared__ float in_lds[15 * 5 * 14];  // 1050 floats, [cl][r][col]
    __shared__ int f2;

    int b = blockIdx.x;
    int ph = b % 27;  b /= 27;
    int pwg = b % 7;  b /= 7;
    int ocg = b % 4;  b /= 4;
    int t = b;
    int oc0 = ocg * 64, pw0 = pwg * 4;
    int tid = threadIdx.x;
    int ocl = tid & 63, pwl = tid >> 6;  // wave-uniform pwl -> input broadcast
    int i0 = 3 * ph, j0 = 3 * pw0;       // padded-84 coords
    int cbase = 3 * pwl;

    // receptive field rows 3ph-2..3ph+2, cols 12pwg-2..12pwg+11 in pool1 coords
    {
        int rlo = i0 - 2; if (rlo < 0) rlo = 0;
        int rhi = i0 + 2; if (rhi > 79) rhi = 79;
        int clo = j0 - 2; if (clo < 0) clo = 0;
        int chi = j0 + 11; if (chi > 79) chi = 79;
        unsigned int f = 0;
        for (int rt = rlo >> 4; rt <= (rhi >> 4); ++rt)
            for (int ct = clo >> 4; ct <= (chi >> 4); ++ct)
                f |= flags1[t * 25 + rt * 5 + ct];
        if (f == 0) {
            int oc = oc0 + ocl, pw = pw0 + pwl;
            if (oc < 250 && pw < 27)
                pool2[((t * 250 + oc) * 27 + ph) * 27 + pw] = 0;
            return;  // flags2 stays 0 (pre-zeroed)
        }
    }
    if (tid == 0) f2 = 0;

    float acc[3][3];
#pragma unroll
    for (int i = 0; i < 3; ++i)
#pragma unroll
        for (int j = 0; j < 3; ++j) acc[i][j] = 0.f;

    for (int ch = 0; ch < 2; ++ch) {  // channel chunks of 15
        for (int idx = tid; idx < 15 * 9 * 64; idx += 256) {
            int o = idx & 63, ckl = idx >> 6;  // ckl in [0,135)
            int oc = oc0 + o;
            int ckg = ch * 135 + ckl;
            w_lds[idx] = (oc < 250) ? w2t[ckg * 250 + oc] : 0.f;
        }
        for (int idx = tid; idx < 15 * 5 * 14; idx += 256) {
            int cl = idx / 70;
            int rem = idx % 70;
            int r = rem / 14, col = rem % 14;
            int gr = i0 + r - 2, gc = j0 + col - 2;
            float v = 0.f;
            if ((unsigned)gr < 80u && (unsigned)gc < 80u)
                v = (float)pool1[((t * 30 + ch * 15 + cl) * 80 + gr) * 80 + gc];
            in_lds[idx] = v;
        }
        __syncthreads();

        for (int cl = 0; cl < 15; ++cl) {
            float in[5][5];
#pragma unroll
            for (int r = 0; r < 5; ++r)
#pragma unroll
                for (int j = 0; j < 5; ++j)
                    in[r][j] = in_lds[cl * 70 + r * 14 + cbase + j];
            const float* wp = &w_lds[cl * 576 + ocl];
#pragma unroll
            for (int k = 0; k < 9; ++k) {
                float w = wp[k * 64];
                int kh = k / 3, kw = k % 3;
#pragma unroll
                for (int i = 0; i < 3; ++i)
#pragma unroll
                    for (int j = 0; j < 3; ++j)
                        acc[i][j] += in[i + kh][j + kw] * w;
            }
        }
        __syncthreads();
    }

    bool s = false;
#pragma unroll
    for (int i = 0; i < 3; ++i)
#pragma unroll
        for (int j = 0; j < 3; ++j) s = s || (acc[i][j] > 1.f);

    int oc = oc0 + ocl, pw = pw0 + pwl;
    bool valid = (oc < 250 && pw < 27);
    if (valid)
        pool2[((t * 250 + oc) * 27 + ph) * 27 + pw] = s ? (unsigned char)1
                                                        : (unsigned char)0;
    if (valid && s) f2 = 1;
    __syncthreads();
    if (tid == 0 && f2) flags2[t * 27 + ph] = 1u;
}

// ---------------- conv3(3x3) + fire(25.0) -> out [spk|pot] (20,200,29,29) x2
// block: (t, 5 oc-groups of 40, 15 row-pairs), 320 thr = 40oc x 8 col-tiles(4)
// Early-out via flags2 rows r0-2..r0+1.
__global__ __launch_bounds__(320) void k_conv3(const unsigned char* __restrict__ pool2,
                                               const float* __restrict__ w3t,
                                               float* __restrict__ out,
                                               const unsigned int* __restrict__ flags2) {
    __shared__ float w_lds[25 * 9 * 40];   // 9000 floats, [ck_local][ocl]
    __shared__ float in_lds[25 * 4 * 34];  // 3400 floats, [cl][r][col]

    int b = blockIdx.x;
    int rb = b % 15;  b /= 15;
    int ocg = b % 5;  b /= 5;
    int t = b;
    int oc0 = ocg * 40;
    int r0 = 2 * rb;  // output rows r0, r0+1
    int tid = threadIdx.x;
    int ocl = tid % 40, ct = tid / 40;  // ct in [0,8)

    float acc[2][4];
#pragma unroll
    for (int i = 0; i < 2; ++i)
#pragma unroll
        for (int j = 0; j < 4; ++j) acc[i][j] = 0.f;

    // receptive field: pool2 rows r0-2..r0+1
    {
        unsigned int f = 0;
        int rlo = r0 - 2; if (rlo < 0) rlo = 0;
        int rhi = r0 + 1; if (rhi > 26) rhi = 26;
        for (int r = rlo; r <= rhi; ++r) f |= flags2[t * 27 + r];
        if (f == 0) goto epilogue;  // acc stays zero -> exact zeros out
    }

    for (int chn = 0; chn < 10; ++chn) {  // channel chunks of 25
        int cc0 = chn * 25;
        for (int idx = tid; idx < 25 * 9 * 40; idx += 320) {
            int o = idx % 40, ck = idx / 40;
            int ckg = cc0 * 9 + ck;
            w_lds[idx] = w3t[ckg * 200 + oc0 + o];
        }
        for (int idx = tid; idx < 25 * 4 * 34; idx += 320) {
            int col = idx % 34;
            int rem = idx / 34;
            int r = rem & 3, cl = rem >> 2;
            int gr = r0 + r - 2, gc = col - 2;
            float v = 0.f;
            if ((unsigned)gr < 27u && (unsigned)gc < 27u)
                v = (float)pool2[((t * 250 + cc0 + cl) * 27 + gr) * 27 + gc];
            in_lds[idx] = v;
        }
        __syncthreads();

        for (int cl = 0; cl < 25; ++cl) {
            float in[4][6];
#pragma unroll
            for (int r = 0; r < 4; ++r)
#pragma unroll
                for (int j = 0; j < 6; ++j)
                    in[r][j] = in_lds[(cl * 4 + r) * 34 + ct * 4 + j];
            const float* wp = &w_lds[cl * 360 + ocl];
#pragma unroll
            for (int k = 0; k < 9; ++k) {
                float w = wp[k * 40];
                int kh = k / 3, kw = k % 3;
#pragma unroll
                for (int i = 0; i < 2; ++i)
#pragma unroll
                    for (int j = 0; j < 4; ++j)
                        acc[i][j] += in[i + kh][j + kw] * w;
            }
        }
        __syncthreads();
    }

epilogue:
    int oc = oc0 + ocl;  // always < 200
#pragma unroll
    for (int i = 0; i < 2; ++i) {
        int r = r0 + i;
        if (r < 29) {
#pragma unroll
            for (int j = 0; j < 4; ++j) {
                int col = ct * 4 + j;
                if (col < 29) {
                    float pot = acc[i][j];
                    bool s = pot > 25.f;
                    size_t base = ((size_t)((t * 200 + oc) * 29 + r)) * 29 + col;
                    out[base] = s ? 1.f : 0.f;
                    out[OUT_HALF + base] = s ? pot : 0.f;
                }
            }
        }
    }
}

extern "C" void kernel_launch(void* const* d_in, const int* in_sizes, int n_in,
                              void* d_out, int out_size, void* d_ws, size_t ws_size,
                              hipStream_t stream) {
    const float* x  = (const float*)d_in[0];
    const float* w1 = (const float*)d_in[1];
    const float* w2 = (const float*)d_in[2];
    const float* w3 = (const float*)d_in[3];
    float* out = (float*)d_out;

    // workspace layout (bytes):
    //   pool1 u8 : [0, 3,840,000)            20*30*80*80
    //   pool2 u8 : [3,840,000, 7,485,000)    20*250*27*27
    //   w2t  f32 : [7,485,056, +270,000)     270x250
    //   w3t  f32 : [7,755,264, +1,800,000)   2250x200
    //   flags1   : [9,555,264, +2,000)       u32[20*5*5]
    //   flags2   : [9,557,312, +2,160)       u32[20*27]
    unsigned char* pool1 = (unsigned char*)d_ws;
    unsigned char* pool2 = pool1 + 3840000;
    float* w2t = (float*)((char*)d_ws + 7485056);
    float* w3t = (float*)((char*)d_ws + 7755264);
    unsigned int* flags1 = (unsigned int*)((char*)d_ws + 9555264);
    unsigned int* flags2 = (unsigned int*)((char*)d_ws + 9557312);

    k_transpose<<<(250 * 270 + 255) / 256, 256, 0, stream>>>(w2, w2t, 250, 270,
                                                             nullptr, 0);
    k_transpose<<<(200 * 2250 + 255) / 256, 256, 0, stream>>>(w3, w3t, 200, 2250,
                                                              flags2, 540);
    k_conv1<<<20 * 5 * 5, 256, 0, stream>>>(x, w1, pool1, flags1);
    k_conv2<<<20 * 4 * 7 * 27, 256, 0, stream>>>(pool1, w2t, pool2, flags1, flags2);
    k_conv3<<<20 * 5 * 15, 320, 0, stream>>>(pool2, w3t, out, flags2);
}

// Round 3
// 175.580 us; speedup vs baseline: 6.0329x; 4.8781x over previous
//
#include <hip/hip_runtime.h>

// deepSNN forward, layer_idx=3 path, fp32 exact, element-sparse conv2.
// x:(20,6,160,160) w1:(30,6,4,4) w2:(250,30,3,3) w3:(200,250,3,3)
// pipeline: pad2->conv1->fire(1)->pool2x2 -> pad2->conv2->fire(1)->pool3x3
//           -> pad2->conv3->fire(25) -> out = [spk | pot] (2 x 20*200*29*29 fp32)
//
// Sparsity facts (measured r2): pool1 has spikes in every 16x16 tile (tile
// flags useless) but pool2 is empty (absmax==0 exact). conv2 therefore runs
// as an exact sparse scatter-stamp over pool1 spike bits: FLOPs = n_spikes *
// 250 * 9 <= dense always, ~100x less at ~1% density. conv3 early-outs on
// per-row flags (round-2 bug: only 256/540 flag words were zeroed -> half the
// conv3 blocks ran dense; fixed with strided loop).

#define OUT_HALF 3364000  // 20*200*29*29

// ---------------- weight transpose: w[oc][ck] -> wt[ck][oc]; also zero flags2
__global__ void k_transpose(const float* __restrict__ w, float* __restrict__ wt,
                            int OC, int CK, unsigned int* zp, int zn) {
    if (blockIdx.x == 0 && zp) {
        for (int i = threadIdx.x; i < zn; i += 256) zp[i] = 0u;  // FIXED: strided
    }
    int idx = blockIdx.x * 256 + threadIdx.x;
    if (idx < OC * CK) {
        int oc = idx / CK, ck = idx % CK;
        wt[ck * OC + oc] = w[idx];
    }
}

// ---------------- conv1(4x4) + fire(1.0) + pool2x2 -> mask1 u32 (20,80,80)
// mask1[t][r][col] bit c = spike in pool1 channel c at (r,col).
// block: (t, 5 row-tiles of 16, 5 col-tiles of 16), 256 thr = one pool cell ea.
__global__ __launch_bounds__(256) void k_conv1(const float* __restrict__ x,
                                               const float* __restrict__ w1,
                                               unsigned int* __restrict__ mask1) {
    __shared__ float in_lds[6 * 35 * 35];  // 7350 floats
    __shared__ float w_lds[30 * 96];       // 2880 floats

    int b = blockIdx.x;
    int colt = b % 5;  b /= 5;
    int rowt = b % 5;  b /= 5;
    int t = b;
    int ph0 = rowt * 16, pw0 = colt * 16;
    int i0 = 2 * ph0, j0 = 2 * pw0;  // padded-164 coords of tile conv origin
    int tid = threadIdx.x;

    for (int idx = tid; idx < 6 * 35 * 35; idx += 256) {
        int c = idx / 1225;
        int rem = idx % 1225;
        int r = rem / 35, col = rem % 35;
        int gr = i0 + r - 2, gc = j0 + col - 2;
        float v = 0.f;
        if ((unsigned)gr < 160u && (unsigned)gc < 160u)
            v = x[((t * 6 + c) * 160 + gr) * 160 + gc];
        in_lds[idx] = v;
    }
    for (int idx = tid; idx < 2880; idx += 256) w_lds[idx] = w1[idx];
    __syncthreads();

    int pw_l = tid & 15, ph_l = tid >> 4;
    int rb = 2 * ph_l, cb = 2 * pw_l;
    unsigned int msk = 0;

    for (int occ = 0; occ < 5; ++occ) {  // 5 chunks of 6 output channels
        float acc[6][4];
#pragma unroll
        for (int o = 0; o < 6; ++o)
#pragma unroll
            for (int p = 0; p < 4; ++p) acc[o][p] = 0.f;

        for (int c = 0; c < 6; ++c) {
            float in[5][5];
#pragma unroll
            for (int r = 0; r < 5; ++r)
#pragma unroll
                for (int cc = 0; cc < 5; ++cc)
                    in[r][cc] = in_lds[c * 1225 + (rb + r) * 35 + cb + cc];
#pragma unroll
            for (int o = 0; o < 6; ++o) {
                const float* wp = &w_lds[(occ * 6 + o) * 96 + c * 16];
#pragma unroll
                for (int kh = 0; kh < 4; ++kh)
#pragma unroll
                    for (int kw = 0; kw < 4; ++kw) {
                        float w = wp[kh * 4 + kw];
                        acc[o][0] += in[kh][kw] * w;
                        acc[o][1] += in[kh][kw + 1] * w;
                        acc[o][2] += in[kh + 1][kw] * w;
                        acc[o][3] += in[kh + 1][kw + 1] * w;
                    }
            }
        }
#pragma unroll
        for (int o = 0; o < 6; ++o) {
            bool s = acc[o][0] > 1.f || acc[o][1] > 1.f ||
                     acc[o][2] > 1.f || acc[o][3] > 1.f;
            if (s) msk |= 1u << (occ * 6 + o);
        }
    }
    mask1[(t * 80 + ph0 + ph_l) * 80 + pw0 + pw_l] = msk;
}

// ---------------- sparse conv2(3x3) + fire(1.0) + pool3x3 -> pool2 u8
// block: (t, 4 oc-groups of 64, 7 pw-groups of 4, 27 ph), 256 thr = 64oc x 4pw.
// Each thread: 3x3 conv patch (one pool cell) for one oc, accumulated by
// iterating spike bits of the 5x5 mask window (wave-uniform; pwl = tid>>6).
// Per spike: <=9 lane-coalesced weight loads (w2t[ck][oc]) + FMAs. Exact.
__global__ __launch_bounds__(256) void k_conv2(const unsigned int* __restrict__ mask1,
                                               const float* __restrict__ w2t,
                                               unsigned char* __restrict__ pool2,
                                               unsigned int* __restrict__ flags2) {
    __shared__ unsigned int m_lds[70];  // 5 rows x 14 cols
    __shared__ int f2;

    int b = blockIdx.x;
    int ph = b % 27;  b /= 27;
    int pwg = b % 7;  b /= 7;
    int ocg = b % 4;  b /= 4;
    int t = b;
    int oc0 = ocg * 64, pw0 = pwg * 4;
    int tid = threadIdx.x;
    int ocl = tid & 63, pwl = tid >> 6;
    int r0 = 3 * ph - 2;    // pool1 row of window origin
    int c0 = 12 * pwg - 2;  // pool1 col of window origin

    if (tid == 0) f2 = 0;
    if (tid < 70) {
        int r = tid / 14, col = tid % 14;
        int gr = r0 + r, gc = c0 + col;
        unsigned int v = 0;
        if ((unsigned)gr < 80u && (unsigned)gc < 80u)
            v = mask1[(t * 80 + gr) * 80 + gc];
        m_lds[tid] = v;
    }
    __syncthreads();

    float acc[3][3];
#pragma unroll
    for (int i = 0; i < 3; ++i)
#pragma unroll
        for (int j = 0; j < 3; ++j) acc[i][j] = 0.f;

    // oc0+ocl can reach 255 for ocg==3: stray reads land in w3t region of the
    // same d_ws allocation (safe); those lanes' stores are masked below.
    const float* wb = w2t + oc0 + ocl;
    int lc0 = 3 * pwl;

#pragma unroll
    for (int dr = 0; dr < 5; ++dr) {
#pragma unroll
        for (int ds = 0; ds < 5; ++ds) {
            unsigned int m = m_lds[dr * 14 + lc0 + ds];
            while (m) {
                int c = __builtin_ctz(m);
                m &= m - 1;
                const float* wc = wb + c * (9 * 250);
#pragma unroll
                for (int i = 0; i < 3; ++i) {
                    if (dr - i >= 0 && dr - i <= 2) {
#pragma unroll
                        for (int j = 0; j < 3; ++j) {
                            if (ds - j >= 0 && ds - j <= 2)
                                acc[i][j] += wc[((dr - i) * 3 + (ds - j)) * 250];
                        }
                    }
                }
            }
        }
    }

    bool s = false;
#pragma unroll
    for (int i = 0; i < 3; ++i)
#pragma unroll
        for (int j = 0; j < 3; ++j) s = s || (acc[i][j] > 1.f);

    int oc = oc0 + ocl, pw = pw0 + pwl;
    bool valid = (oc < 250 && pw < 27);
    if (valid)
        pool2[((t * 250 + oc) * 27 + ph) * 27 + pw] = s ? (unsigned char)1
                                                        : (unsigned char)0;
    if (valid && s) f2 = 1;  // same-value LDS stores, race-safe
    __syncthreads();
    if (tid == 0 && f2) flags2[t * 27 + ph] = 1u;
}

// ---------------- conv3(3x3) + fire(25.0) -> out [spk|pot] (20,200,29,29) x2
// block: (t, 5 oc-groups of 40, 15 row-pairs), 320 thr = 40oc x 8 col-tiles(4)
// Early-out via flags2 rows r0-2..r0+1 -> coalesced zero-fill.
__global__ __launch_bounds__(320) void k_conv3(const unsigned char* __restrict__ pool2,
                                               const float* __restrict__ w3t,
                                               float* __restrict__ out,
                                               const unsigned int* __restrict__ flags2) {
    __shared__ float w_lds[25 * 9 * 40];   // 9000 floats, [ck_local][ocl]
    __shared__ float in_lds[25 * 4 * 34];  // 3400 floats, [cl][r][col]

    int b = blockIdx.x;
    int rb = b % 15;  b /= 15;
    int ocg = b % 5;  b /= 5;
    int t = b;
    int oc0 = ocg * 40;
    int r0 = 2 * rb;  // output rows r0, r0+1
    int tid = threadIdx.x;
    int ocl = tid % 40, ct = tid / 40;  // ct in [0,8)

    // receptive field: pool2 rows r0-2..r0+1
    {
        unsigned int f = 0;
        int rlo = r0 - 2; if (rlo < 0) rlo = 0;
        int rhi = r0 + 1; if (rhi > 26) rhi = 26;
        for (int r = rlo; r <= rhi; ++r) f |= flags2[t * 27 + r];
        if (f == 0) {
            // exact zeros, coalesced: rows r0..r0+nrows-1, all 29 cols, 40 ocs
            int nrows = (r0 + 1 < 29) ? 2 : 1;
            int stride = 29 * nrows;
            int cnt = 40 * stride;
            for (int idx = tid; idx < cnt; idx += 320) {
                int o = idx / stride, rem = idx % stride;
                size_t base = (size_t)((t * 200 + oc0 + o) * 29 + r0) * 29 + rem;
                out[base] = 0.f;
                out[OUT_HALF + base] = 0.f;
            }
            return;
        }
    }

    float acc[2][4];
#pragma unroll
    for (int i = 0; i < 2; ++i)
#pragma unroll
        for (int j = 0; j < 4; ++j) acc[i][j] = 0.f;

    for (int chn = 0; chn < 10; ++chn) {  // channel chunks of 25
        int cc0 = chn * 25;
        for (int idx = tid; idx < 25 * 9 * 40; idx += 320) {
            int o = idx % 40, ck = idx / 40;
            int ckg = cc0 * 9 + ck;
            w_lds[idx] = w3t[ckg * 200 + oc0 + o];
        }
        for (int idx = tid; idx < 25 * 4 * 34; idx += 320) {
            int col = idx % 34;
            int rem = idx / 34;
            int r = rem & 3, cl = rem >> 2;
            int gr = r0 + r - 2, gc = col - 2;
            float v = 0.f;
            if ((unsigned)gr < 27u && (unsigned)gc < 27u)
                v = (float)pool2[((t * 250 + cc0 + cl) * 27 + gr) * 27 + gc];
            in_lds[idx] = v;
        }
        __syncthreads();

        for (int cl = 0; cl < 25; ++cl) {
            float in[4][6];
#pragma unroll
            for (int r = 0; r < 4; ++r)
#pragma unroll
                for (int j = 0; j < 6; ++j)
                    in[r][j] = in_lds[(cl * 4 + r) * 34 + ct * 4 + j];
            const float* wp = &w_lds[cl * 360 + ocl];
#pragma unroll
            for (int k = 0; k < 9; ++k) {
                float w = wp[k * 40];
                int kh = k / 3, kw = k % 3;
#pragma unroll
                for (int i = 0; i < 2; ++i)
#pragma unroll
                    for (int j = 0; j < 4; ++j)
                        acc[i][j] += in[i + kh][j + kw] * w;
            }
        }
        __syncthreads();
    }

    {
        int oc = oc0 + ocl;  // always < 200
#pragma unroll
        for (int i = 0; i < 2; ++i) {
            int r = r0 + i;
            if (r < 29) {
#pragma unroll
                for (int j = 0; j < 4; ++j) {
                    int col = ct * 4 + j;
                    if (col < 29) {
                        float pot = acc[i][j];
                        bool s = pot > 25.f;
                        size_t base = ((size_t)((t * 200 + oc) * 29 + r)) * 29 + col;
                        out[base] = s ? 1.f : 0.f;
                        out[OUT_HALF + base] = s ? pot : 0.f;
                    }
                }
            }
        }
    }
}

extern "C" void kernel_launch(void* const* d_in, const int* in_sizes, int n_in,
                              void* d_out, int out_size, void* d_ws, size_t ws_size,
                              hipStream_t stream) {
    const float* x  = (const float*)d_in[0];
    const float* w1 = (const float*)d_in[1];
    const float* w2 = (const float*)d_in[2];
    const float* w3 = (const float*)d_in[3];
    float* out = (float*)d_out;

    // workspace layout (bytes):
    //   mask1 u32: [0, 512,000)              20*80*80
    //   pool2 u8 : [512,000, 4,157,000)      20*250*27*27
    //   w2t  f32 : [4,157,056, +270,000)     270x250
    //   w3t  f32 : [4,427,264, +1,800,000)   2250x200
    //   flags2   : [6,227,264, +2,160)       u32[20*27]
    unsigned int* mask1 = (unsigned int*)d_ws;
    unsigned char* pool2 = (unsigned char*)d_ws + 512000;
    float* w2t = (float*)((char*)d_ws + 4157056);
    float* w3t = (float*)((char*)d_ws + 4427264);
    unsigned int* flags2 = (unsigned int*)((char*)d_ws + 6227264);

    k_transpose<<<(250 * 270 + 255) / 256, 256, 0, stream>>>(w2, w2t, 250, 270,
                                                             nullptr, 0);
    k_transpose<<<(200 * 2250 + 255) / 256, 256, 0, stream>>>(w3, w3t, 200, 2250,
                                                              flags2, 540);
    k_conv1<<<20 * 5 * 5, 256, 0, stream>>>(x, w1, mask1);
    k_conv2<<<20 * 4 * 7 * 27, 256, 0, stream>>>(mask1, w2t, pool2, flags2);
    k_conv3<<<20 * 5 * 15, 320, 0, stream>>>(pool2, w3t, out, flags2);
}

// Round 4
// 166.049 us; speedup vs baseline: 6.3792x; 1.0574x over previous
//
#include <hip/hip_runtime.h>

// deepSNN forward, layer_idx=3 path, fp32 exact, element-sparse conv2.
// x:(20,6,160,160) w1:(30,6,4,4) w2:(250,30,3,3) w3:(200,250,3,3)
// pipeline: pad2->conv1->fire(1)->pool2x2 -> pad2->conv2->fire(1)->pool3x3
//           -> pad2->conv3->fire(25) -> out = [spk | pot] (2 x 20*200*29*29 fp32)
//
// r3 counters: conv1 62us, VALUBusy 42%, 4.3M LDS bank conflicts (stride-2
// lane pattern -> even banks only, 4-way), 2880 broadcast weight ds_reads per
// thread. r4: conv1 rewritten — permuted-column LDS (conflict-free), float4
// weight reads, all-30-oc accumulation (input reads 750->150), v_pk_fma_f32
// via ext_vector float2 (VALU halved). w3 transpose dropped (conv3 dense path
// reads w3 direct; it never runs — pool2 is empty on this input).

#define OUT_HALF 3364000  // 20*200*29*29

typedef float v2f __attribute__((ext_vector_type(2)));

// ---------------- w2 transpose: w2[oc][ck] -> w2t[ck][oc]; also zero flags2
__global__ void k_transpose(const float* __restrict__ w, float* __restrict__ wt,
                            int OC, int CK, unsigned int* zp, int zn) {
    if (blockIdx.x == 0 && zp) {
        for (int i = threadIdx.x; i < zn; i += 256) zp[i] = 0u;
    }
    int idx = blockIdx.x * 256 + threadIdx.x;
    if (idx < OC * CK) {
        int oc = idx / CK, ck = idx % CK;
        wt[ck * OC + oc] = w[idx];
    }
}

// ---------------- conv1(4x4) + fire(1.0) + pool2x2 -> mask1 u32 (20,80,80)
// block: (t, 5 row-tiles of 16, 5 col-tiles of 16), 256 thr = one pool cell ea.
// LDS input layout: [c][row][perm(col)], row stride 36, perm = col/2 + (col&1)*18
// -> window reads hit bank pw_l + 8*ph_l (+const): exactly 2 lanes/bank = free.
__global__ __launch_bounds__(256, 2) void k_conv1(const float* __restrict__ x,
                                                  const float* __restrict__ w1,
                                                  unsigned int* __restrict__ mask1) {
    __shared__ float in_lds[6 * 35 * 36];       // 30240 B
    __shared__ float4 w_lds4[30 * 24];          // 11520 B, [oc][24 float4]

    int b = blockIdx.x;
    int colt = b % 5;  b /= 5;
    int rowt = b % 5;  b /= 5;
    int t = b;
    int ph0 = rowt * 16, pw0 = colt * 16;
    int i0 = 2 * ph0, j0 = 2 * pw0;  // padded-164 coords of tile conv origin
    int tid = threadIdx.x;

    for (int idx = tid; idx < 6 * 35 * 35; idx += 256) {
        int c = idx / 1225;
        int rem = idx % 1225;
        int r = rem / 35, col = rem % 35;
        int gr = i0 + r - 2, gc = j0 + col - 2;
        float v = 0.f;
        if ((unsigned)gr < 160u && (unsigned)gc < 160u)
            v = x[((t * 6 + c) * 160 + gr) * 160 + gc];
        in_lds[c * 1260 + r * 36 + (col >> 1) + (col & 1) * 18] = v;
    }
    for (int idx = tid; idx < 720; idx += 256)
        w_lds4[idx] = ((const float4*)w1)[idx];
    __syncthreads();

    int pw_l = tid & 15, ph_l = tid >> 4;
    int rb = 2 * ph_l;

    v2f acc01[30], acc23[30];  // positions (0,0),(0,1) and (1,0),(1,1)
#pragma unroll
    for (int o = 0; o < 30; ++o) {
        acc01[o].x = 0.f; acc01[o].y = 0.f;
        acc23[o].x = 0.f; acc23[o].y = 0.f;
    }

#pragma unroll 1
    for (int c = 0; c < 6; ++c) {
        // window cols cb..cb+4 (cb=2*pw_l): permuted offsets 0,18,1,19,2
        const float* pl = &in_lds[c * 1260 + rb * 36 + pw_l];
        float q[5][5];
#pragma unroll
        for (int r = 0; r < 5; ++r) {
            const float* pr = pl + r * 36;
            q[r][0] = pr[0];  q[r][1] = pr[18]; q[r][2] = pr[1];
            q[r][3] = pr[19]; q[r][4] = pr[2];
        }
        v2f p[5][4];  // p[r][k] = {in[r][k], in[r][k+1]}
#pragma unroll
        for (int r = 0; r < 5; ++r)
#pragma unroll
            for (int k = 0; k < 4; ++k) {
                p[r][k].x = q[r][k];
                p[r][k].y = q[r][k + 1];
            }
#pragma unroll
        for (int o = 0; o < 30; ++o) {
            const float4* wp = w_lds4 + o * 24 + c * 4;
#pragma unroll
            for (int kh = 0; kh < 4; ++kh) {
                float4 wv = wp[kh];
                float wk0 = wv.x, wk1 = wv.y, wk2 = wv.z, wk3 = wv.w;
                v2f wb;
                wb.x = wk0; wb.y = wk0;
                acc01[o] += p[kh][0] * wb;  acc23[o] += p[kh + 1][0] * wb;
                wb.x = wk1; wb.y = wk1;
                acc01[o] += p[kh][1] * wb;  acc23[o] += p[kh + 1][1] * wb;
                wb.x = wk2; wb.y = wk2;
                acc01[o] += p[kh][2] * wb;  acc23[o] += p[kh + 1][2] * wb;
                wb.x = wk3; wb.y = wk3;
                acc01[o] += p[kh][3] * wb;  acc23[o] += p[kh + 1][3] * wb;
            }
        }
    }

    unsigned int msk = 0;
#pragma unroll
    for (int o = 0; o < 30; ++o) {
        bool s = acc01[o].x > 1.f || acc01[o].y > 1.f ||
                 acc23[o].x > 1.f || acc23[o].y > 1.f;
        if (s) msk |= 1u << o;
    }
    mask1[(t * 80 + ph0 + ph_l) * 80 + pw0 + pw_l] = msk;
}

// ---------------- sparse conv2(3x3) + fire(1.0) + pool3x3 -> pool2 u8
// block: (t, 4 oc-groups of 64, 7 pw-groups of 4, 27 ph), 256 thr = 64oc x 4pw.
// Per-thread 3x3 patch for one oc; iterate spike bits of the 5x5 mask window
// (wave-uniform). Per spike: <=9 lane-coalesced weight loads + FMAs. Exact.
__global__ __launch_bounds__(256) void k_conv2(const unsigned int* __restrict__ mask1,
                                               const float* __restrict__ w2t,
                                               unsigned char* __restrict__ pool2,
                                               unsigned int* __restrict__ flags2) {
    __shared__ unsigned int m_lds[70];  // 5 rows x 14 cols
    __shared__ int f2;

    int b = blockIdx.x;
    int ph = b % 27;  b /= 27;
    int pwg = b % 7;  b /= 7;
    int ocg = b % 4;  b /= 4;
    int t = b;
    int oc0 = ocg * 64, pw0 = pwg * 4;
    int tid = threadIdx.x;
    int ocl = tid & 63, pwl = tid >> 6;
    int r0 = 3 * ph - 2;    // pool1 row of window origin
    int c0 = 12 * pwg - 2;  // pool1 col of window origin

    if (tid == 0) f2 = 0;
    if (tid < 70) {
        int r = tid / 14, col = tid % 14;
        int gr = r0 + r, gc = c0 + col;
        unsigned int v = 0;
        if ((unsigned)gr < 80u && (unsigned)gc < 80u)
            v = mask1[(t * 80 + gr) * 80 + gc];
        m_lds[tid] = v;
    }
    __syncthreads();

    float acc[3][3];
#pragma unroll
    for (int i = 0; i < 3; ++i)
#pragma unroll
        for (int j = 0; j < 3; ++j) acc[i][j] = 0.f;

    // oc0+ocl can reach 255 for ocg==3: stray reads land in the pad region
    // after w2t (safe); those lanes' stores are masked below.
    const float* wb = w2t + oc0 + ocl;
    int lc0 = 3 * pwl;

#pragma unroll
    for (int dr = 0; dr < 5; ++dr) {
#pragma unroll
        for (int ds = 0; ds < 5; ++ds) {
            unsigned int m = m_lds[dr * 14 + lc0 + ds];
            while (m) {
                int c = __builtin_ctz(m);
                m &= m - 1;
                const float* wc = wb + c * (9 * 250);
#pragma unroll
                for (int i = 0; i < 3; ++i) {
                    if (dr - i >= 0 && dr - i <= 2) {
#pragma unroll
                        for (int j = 0; j < 3; ++j) {
                            if (ds - j >= 0 && ds - j <= 2)
                                acc[i][j] += wc[((dr - i) * 3 + (ds - j)) * 250];
                        }
                    }
                }
            }
        }
    }

    bool s = false;
#pragma unroll
    for (int i = 0; i < 3; ++i)
#pragma unroll
        for (int j = 0; j < 3; ++j) s = s || (acc[i][j] > 1.f);

    int oc = oc0 + ocl, pw = pw0 + pwl;
    bool valid = (oc < 250 && pw < 27);
    if (valid)
        pool2[((t * 250 + oc) * 27 + ph) * 27 + pw] = s ? (unsigned char)1
                                                        : (unsigned char)0;
    if (valid && s) f2 = 1;  // same-value LDS stores, race-safe
    __syncthreads();
    if (tid == 0 && f2) flags2[t * 27 + ph] = 1u;
}

// ---------------- conv3(3x3) + fire(25.0) -> out [spk|pot] (20,200,29,29) x2
// block: (t, 5 oc-groups of 40, 15 row-pairs), 320 thr = 40oc x 8 col-tiles(4)
// Early-out via flags2 rows r0-2..r0+1 -> coalesced zero-fill. Dense path
// stages w3 directly (uncoalesced but never executed when pool2 is empty).
__global__ __launch_bounds__(320) void k_conv3(const unsigned char* __restrict__ pool2,
                                               const float* __restrict__ w3,
                                               float* __restrict__ out,
                                               const unsigned int* __restrict__ flags2) {
    __shared__ float w_lds[25 * 9 * 40];   // 9000 floats, [ck_local][ocl]
    __shared__ float in_lds[25 * 4 * 34];  // 3400 floats, [cl][r][col]

    int b = blockIdx.x;
    int rb = b % 15;  b /= 15;
    int ocg = b % 5;  b /= 5;
    int t = b;
    int oc0 = ocg * 40;
    int r0 = 2 * rb;  // output rows r0, r0+1
    int tid = threadIdx.x;
    int ocl = tid % 40, ct = tid / 40;  // ct in [0,8)

    // receptive field: pool2 rows r0-2..r0+1
    {
        unsigned int f = 0;
        int rlo = r0 - 2; if (rlo < 0) rlo = 0;
        int rhi = r0 + 1; if (rhi > 26) rhi = 26;
        for (int r = rlo; r <= rhi; ++r) f |= flags2[t * 27 + r];
        if (f == 0) {
            // exact zeros, coalesced: rows r0..r0+nrows-1, all 29 cols, 40 ocs
            int nrows = (r0 + 1 < 29) ? 2 : 1;
            int stride = 29 * nrows;
            int cnt = 40 * stride;
            for (int idx = tid; idx < cnt; idx += 320) {
                int o = idx / stride, rem = idx % stride;
                size_t base = (size_t)((t * 200 + oc0 + o) * 29 + r0) * 29 + rem;
                out[base] = 0.f;
                out[OUT_HALF + base] = 0.f;
            }
            return;
        }
    }

    float acc[2][4];
#pragma unroll
    for (int i = 0; i < 2; ++i)
#pragma unroll
        for (int j = 0; j < 4; ++j) acc[i][j] = 0.f;

    for (int chn = 0; chn < 10; ++chn) {  // channel chunks of 25
        int cc0 = chn * 25;
        for (int idx = tid; idx < 25 * 9 * 40; idx += 320) {
            int o = idx % 40, ck = idx / 40;         // ck in [0,225)
            int ckg = cc0 * 9 + ck;                  // global (c,kh,kw) index
            w_lds[idx] = w3[(size_t)(oc0 + o) * 2250 + ckg];
        }
        for (int idx = tid; idx < 25 * 4 * 34; idx += 320) {
            int col = idx % 34;
            int rem = idx / 34;
            int r = rem & 3, cl = rem >> 2;
            int gr = r0 + r - 2, gc = col - 2;
            float v = 0.f;
            if ((unsigned)gr < 27u && (unsigned)gc < 27u)
                v = (float)pool2[((t * 250 + cc0 + cl) * 27 + gr) * 27 + gc];
            in_lds[idx] = v;
        }
        __syncthreads();

        for (int cl = 0; cl < 25; ++cl) {
            float in[4][6];
#pragma unroll
            for (int r = 0; r < 4; ++r)
#pragma unroll
                for (int j = 0; j < 6; ++j)
                    in[r][j] = in_lds[(cl * 4 + r) * 34 + ct * 4 + j];
            const float* wp = &w_lds[cl * 360 + ocl];
#pragma unroll
            for (int k = 0; k < 9; ++k) {
                float w = wp[k * 40];
                int kh = k / 3, kw = k % 3;
#pragma unroll
                for (int i = 0; i < 2; ++i)
#pragma unroll
                    for (int j = 0; j < 4; ++j)
                        acc[i][j] += in[i + kh][j + kw] * w;
            }
        }
        __syncthreads();
    }

    {
        int oc = oc0 + ocl;  // always < 200
#pragma unroll
        for (int i = 0; i < 2; ++i) {
            int r = r0 + i;
            if (r < 29) {
#pragma unroll
                for (int j = 0; j < 4; ++j) {
                    int col = ct * 4 + j;
                    if (col < 29) {
                        float pot = acc[i][j];
                        bool s = pot > 25.f;
                        size_t base = ((size_t)((t * 200 + oc) * 29 + r)) * 29 + col;
                        out[base] = s ? 1.f : 0.f;
                        out[OUT_HALF + base] = s ? pot : 0.f;
                    }
                }
            }
        }
    }
}

extern "C" void kernel_launch(void* const* d_in, const int* in_sizes, int n_in,
                              void* d_out, int out_size, void* d_ws, size_t ws_size,
                              hipStream_t stream) {
    const float* x  = (const float*)d_in[0];
    const float* w1 = (const float*)d_in[1];
    const float* w2 = (const float*)d_in[2];
    const float* w3 = (const float*)d_in[3];
    float* out = (float*)d_out;

    // workspace layout (bytes):
    //   mask1 u32: [0, 512,000)              20*80*80
    //   pool2 u8 : [512,000, 4,157,000)      20*250*27*27
    //   w2t  f32 : [4,157,056, +270,000)     270x250  (ends 4,427,056)
    //   pad      : [4,427,056, 4,431,872)    absorbs conv2 stray oc reads
    //   flags2   : [4,431,872, +2,160)       u32[20*27]
    unsigned int* mask1 = (unsigned int*)d_ws;
    unsigned char* pool2 = (unsigned char*)d_ws + 512000;
    float* w2t = (float*)((char*)d_ws + 4157056);
    unsigned int* flags2 = (unsigned int*)((char*)d_ws + 4431872);

    k_transpose<<<(250 * 270 + 255) / 256, 256, 0, stream>>>(w2, w2t, 250, 270,
                                                             flags2, 540);
    k_conv1<<<20 * 5 * 5, 256, 0, stream>>>(x, w1, mask1);
    k_conv2<<<20 * 4 * 7 * 27, 256, 0, stream>>>(mask1, w2t, pool2, flags2);
    k_conv3<<<20 * 5 * 15, 320, 0, stream>>>(pool2, w3, out, flags2);
}

// Round 5
// 153.190 us; speedup vs baseline: 6.9147x; 1.0839x over previous
//
#include <hip/hip_runtime.h>

// deepSNN forward, layer_idx=3 path, fp32 exact, element-sparse conv2.
// x:(20,6,160,160) w1:(30,6,4,4) w2:(250,30,3,3) w3:(200,250,3,3)
// pipeline: pad2->conv1->fire(1)->pool2x2 -> pad2->conv2->fire(1)->pool3x3
//           -> pad2->conv3->fire(25) -> out = [spk | pot] (2 x 20*200*29*29 fp32)
//
// r4 post-mortem: conv1 co-bound on LDS pipe (broadcast weight ds_read_b128
// ~12cyc each, 720/wave ~= FMA time) and VALU, at only ~8 waves/CU (grid-
// limited). r5: weights read straight from global with wave-uniform indices
// (scalar-pipe s_load, zero LDS traffic), oc split 2x (1000 blocks, 15 oc
// each, half the acc registers) -> mask1 stored as two 15-bit planes that
// conv2 ORs together at stage time.

#define OUT_HALF 3364000  // 20*200*29*29
#define MASK_PLANE 128000 // 20*80*80

typedef float v2f __attribute__((ext_vector_type(2)));

// ---------------- w2 transpose: w2[oc][ck] -> w2t[ck][oc]; also zero flags2
__global__ void k_transpose(const float* __restrict__ w, float* __restrict__ wt,
                            int OC, int CK, unsigned int* zp, int zn) {
    if (blockIdx.x == 0 && zp) {
        for (int i = threadIdx.x; i < zn; i += 256) zp[i] = 0u;
    }
    int idx = blockIdx.x * 256 + threadIdx.x;
    if (idx < OC * CK) {
        int oc = idx / CK, ck = idx % CK;
        wt[ck * OC + oc] = w[idx];
    }
}

// ---------------- conv1(4x4) + fire(1.0) + pool2x2 -> mask1 u32, 2 planes
// block: (t, 5 row-tiles, 5 col-tiles, 2 oc-halves), 256 thr = one pool cell.
// mask1[h*MASK_PLANE + (t*80+r)*80+c] bits 0..14 = spikes of oc h*15..h*15+14.
// Input LDS layout: [c][row][perm(col)], perm = col/2 + (col&1)*18 -> window
// reads hit 2 lanes/bank (free). Weights: wave-uniform global float4 loads
// (scalar pipe), never touch LDS.
__global__ __launch_bounds__(256, 3) void k_conv1(const float* __restrict__ x,
                                                  const float* __restrict__ w1,
                                                  unsigned int* __restrict__ mask1) {
    __shared__ float in_lds[6 * 35 * 36];  // 30240 B

    int b = blockIdx.x;
    int h = b & 1;     b >>= 1;  // oc half: 0 -> oc 0..14, 1 -> oc 15..29
    int colt = b % 5;  b /= 5;
    int rowt = b % 5;  b /= 5;
    int t = b;
    int ph0 = rowt * 16, pw0 = colt * 16;
    int i0 = 2 * ph0, j0 = 2 * pw0;  // padded-164 coords of tile conv origin
    int tid = threadIdx.x;

    for (int idx = tid; idx < 6 * 35 * 35; idx += 256) {
        int c = idx / 1225;
        int rem = idx % 1225;
        int r = rem / 35, col = rem % 35;
        int gr = i0 + r - 2, gc = j0 + col - 2;
        float v = 0.f;
        if ((unsigned)gr < 160u && (unsigned)gc < 160u)
            v = x[((t * 6 + c) * 160 + gr) * 160 + gc];
        in_lds[c * 1260 + r * 36 + (col >> 1) + (col & 1) * 18] = v;
    }
    __syncthreads();

    int pw_l = tid & 15, ph_l = tid >> 4;
    int rb = 2 * ph_l;

    v2f acc01[15], acc23[15];  // positions (0,0),(0,1) and (1,0),(1,1)
#pragma unroll
    for (int o = 0; o < 15; ++o) {
        acc01[o] = (v2f)(0.f);
        acc23[o] = (v2f)(0.f);
    }

    // weights for this half: w1[(h*15+o)][c][kh][kw], float4 per (o,c,kh)
    const float4* wq = (const float4*)w1 + h * 15 * 24;

#pragma unroll 1
    for (int c = 0; c < 6; ++c) {
        // window cols cb..cb+4 (cb=2*pw_l): permuted offsets 0,18,1,19,2
        const float* pl = &in_lds[c * 1260 + rb * 36 + pw_l];
        float q[5][5];
#pragma unroll
        for (int r = 0; r < 5; ++r) {
            const float* pr = pl + r * 36;
            q[r][0] = pr[0];  q[r][1] = pr[18]; q[r][2] = pr[1];
            q[r][3] = pr[19]; q[r][4] = pr[2];
        }
        v2f p[5][4];  // p[r][k] = {in[r][k], in[r][k+1]}
#pragma unroll
        for (int r = 0; r < 5; ++r)
#pragma unroll
            for (int k = 0; k < 4; ++k) {
                p[r][k].x = q[r][k];
                p[r][k].y = q[r][k + 1];
            }
#pragma unroll
        for (int o = 0; o < 15; ++o) {
            const float4* wp = wq + o * 24 + c * 4;
#pragma unroll
            for (int kh = 0; kh < 4; ++kh) {
                float4 wv = wp[kh];  // uniform -> scalar regs
                v2f w0 = {wv.x, wv.x}, w1v = {wv.y, wv.y};
                v2f w2v = {wv.z, wv.z}, w3v = {wv.w, wv.w};
                acc01[o] += p[kh][0] * w0;   acc23[o] += p[kh + 1][0] * w0;
                acc01[o] += p[kh][1] * w1v;  acc23[o] += p[kh + 1][1] * w1v;
                acc01[o] += p[kh][2] * w2v;  acc23[o] += p[kh + 1][2] * w2v;
                acc01[o] += p[kh][3] * w3v;  acc23[o] += p[kh + 1][3] * w3v;
            }
        }
    }

    unsigned int msk = 0;
#pragma unroll
    for (int o = 0; o < 15; ++o) {
        bool s = acc01[o].x > 1.f || acc01[o].y > 1.f ||
                 acc23[o].x > 1.f || acc23[o].y > 1.f;
        if (s) msk |= 1u << o;
    }
    mask1[h * MASK_PLANE + (t * 80 + ph0 + ph_l) * 80 + pw0 + pw_l] = msk;
}

// ---------------- sparse conv2(3x3) + fire(1.0) + pool3x3 -> pool2 u8
// block: (t, 4 oc-groups of 64, 7 pw-groups of 4, 27 ph), 256 thr = 64oc x 4pw.
// Per-thread 3x3 patch for one oc; iterate spike bits of the 5x5 mask window
// (wave-uniform). Per spike: <=9 lane-coalesced weight loads + FMAs. Exact.
__global__ __launch_bounds__(256) void k_conv2(const unsigned int* __restrict__ mask1,
                                               const float* __restrict__ w2t,
                                               unsigned char* __restrict__ pool2,
                                               unsigned int* __restrict__ flags2) {
    __shared__ unsigned int m_lds[70];  // 5 rows x 14 cols, 30-bit combined
    __shared__ int f2;

    int b = blockIdx.x;
    int ph = b % 27;  b /= 27;
    int pwg = b % 7;  b /= 7;
    int ocg = b % 4;  b /= 4;
    int t = b;
    int oc0 = ocg * 64, pw0 = pwg * 4;
    int tid = threadIdx.x;
    int ocl = tid & 63, pwl = tid >> 6;
    int r0 = 3 * ph - 2;    // pool1 row of window origin
    int c0 = 12 * pwg - 2;  // pool1 col of window origin

    if (tid == 0) f2 = 0;
    if (tid < 70) {
        int r = tid / 14, col = tid % 14;
        int gr = r0 + r, gc = c0 + col;
        unsigned int v = 0;
        if ((unsigned)gr < 80u && (unsigned)gc < 80u) {
            int idx = (t * 80 + gr) * 80 + gc;
            v = mask1[idx] | (mask1[MASK_PLANE + idx] << 15);
        }
        m_lds[tid] = v;
    }
    __syncthreads();

    float acc[3][3];
#pragma unroll
    for (int i = 0; i < 3; ++i)
#pragma unroll
        for (int j = 0; j < 3; ++j) acc[i][j] = 0.f;

    // oc0+ocl can reach 255 for ocg==3: stray reads land in the pad region
    // after w2t (safe); those lanes' stores are masked below.
    const float* wb = w2t + oc0 + ocl;
    int lc0 = 3 * pwl;

#pragma unroll
    for (int dr = 0; dr < 5; ++dr) {
#pragma unroll
        for (int ds = 0; ds < 5; ++ds) {
            unsigned int m = m_lds[dr * 14 + lc0 + ds];
            while (m) {
                int c = __builtin_ctz(m);
                m &= m - 1;
                const float* wc = wb + c * (9 * 250);
#pragma unroll
                for (int i = 0; i < 3; ++i) {
                    if (dr - i >= 0 && dr - i <= 2) {
#pragma unroll
                        for (int j = 0; j < 3; ++j) {
                            if (ds - j >= 0 && ds - j <= 2)
                                acc[i][j] += wc[((dr - i) * 3 + (ds - j)) * 250];
                        }
                    }
                }
            }
        }
    }

    bool s = false;
#pragma unroll
    for (int i = 0; i < 3; ++i)
#pragma unroll
        for (int j = 0; j < 3; ++j) s = s || (acc[i][j] > 1.f);

    int oc = oc0 + ocl, pw = pw0 + pwl;
    bool valid = (oc < 250 && pw < 27);
    if (valid)
        pool2[((t * 250 + oc) * 27 + ph) * 27 + pw] = s ? (unsigned char)1
                                                        : (unsigned char)0;
    if (valid && s) f2 = 1;  // same-value LDS stores, race-safe
    __syncthreads();
    if (tid == 0 && f2) flags2[t * 27 + ph] = 1u;
}

// ---------------- conv3(3x3) + fire(25.0) -> out [spk|pot] (20,200,29,29) x2
// block: (t, 5 oc-groups of 40, 15 row-pairs), 320 thr = 40oc x 8 col-tiles(4)
// Early-out via flags2 rows r0-2..r0+1 -> coalesced zero-fill. Dense path
// stages w3 directly (uncoalesced but never executed when pool2 is empty).
__global__ __launch_bounds__(320) void k_conv3(const unsigned char* __restrict__ pool2,
                                               const float* __restrict__ w3,
                                               float* __restrict__ out,
                                               const unsigned int* __restrict__ flags2) {
    __shared__ float w_lds[25 * 9 * 40];   // 9000 floats, [ck_local][ocl]
    __shared__ float in_lds[25 * 4 * 34];  // 3400 floats, [cl][r][col]

    int b = blockIdx.x;
    int rb = b % 15;  b /= 15;
    int ocg = b % 5;  b /= 5;
    int t = b;
    int oc0 = ocg * 40;
    int r0 = 2 * rb;  // output rows r0, r0+1
    int tid = threadIdx.x;
    int ocl = tid % 40, ct = tid / 40;  // ct in [0,8)

    // receptive field: pool2 rows r0-2..r0+1
    {
        unsigned int f = 0;
        int rlo = r0 - 2; if (rlo < 0) rlo = 0;
        int rhi = r0 + 1; if (rhi > 26) rhi = 26;
        for (int r = rlo; r <= rhi; ++r) f |= flags2[t * 27 + r];
        if (f == 0) {
            // exact zeros, coalesced: rows r0..r0+nrows-1, all 29 cols, 40 ocs
            int nrows = (r0 + 1 < 29) ? 2 : 1;
            int stride = 29 * nrows;
            int cnt = 40 * stride;
            for (int idx = tid; idx < cnt; idx += 320) {
                int o = idx / stride, rem = idx % stride;
                size_t base = (size_t)((t * 200 + oc0 + o) * 29 + r0) * 29 + rem;
                out[base] = 0.f;
                out[OUT_HALF + base] = 0.f;
            }
            return;
        }
    }

    float acc[2][4];
#pragma unroll
    for (int i = 0; i < 2; ++i)
#pragma unroll
        for (int j = 0; j < 4; ++j) acc[i][j] = 0.f;

    for (int chn = 0; chn < 10; ++chn) {  // channel chunks of 25
        int cc0 = chn * 25;
        for (int idx = tid; idx < 25 * 9 * 40; idx += 320) {
            int o = idx % 40, ck = idx / 40;         // ck in [0,225)
            int ckg = cc0 * 9 + ck;                  // global (c,kh,kw) index
            w_lds[idx] = w3[(size_t)(oc0 + o) * 2250 + ckg];
        }
        for (int idx = tid; idx < 25 * 4 * 34; idx += 320) {
            int col = idx % 34;
            int rem = idx / 34;
            int r = rem & 3, cl = rem >> 2;
            int gr = r0 + r - 2, gc = col - 2;
            float v = 0.f;
            if ((unsigned)gr < 27u && (unsigned)gc < 27u)
                v = (float)pool2[((t * 250 + cc0 + cl) * 27 + gr) * 27 + gc];
            in_lds[idx] = v;
        }
        __syncthreads();

        for (int cl = 0; cl < 25; ++cl) {
            float in[4][6];
#pragma unroll
            for (int r = 0; r < 4; ++r)
#pragma unroll
                for (int j = 0; j < 6; ++j)
                    in[r][j] = in_lds[(cl * 4 + r) * 34 + ct * 4 + j];
            const float* wp = &w_lds[cl * 360 + ocl];
#pragma unroll
            for (int k = 0; k < 9; ++k) {
                float w = wp[k * 40];
                int kh = k / 3, kw = k % 3;
#pragma unroll
                for (int i = 0; i < 2; ++i)
#pragma unroll
                    for (int j = 0; j < 4; ++j)
                        acc[i][j] += in[i + kh][j + kw] * w;
            }
        }
        __syncthreads();
    }

    {
        int oc = oc0 + ocl;  // always < 200
#pragma unroll
        for (int i = 0; i < 2; ++i) {
            int r = r0 + i;
            if (r < 29) {
#pragma unroll
                for (int j = 0; j < 4; ++j) {
                    int col = ct * 4 + j;
                    if (col < 29) {
                        float pot = acc[i][j];
                        bool s = pot > 25.f;
                        size_t base = ((size_t)((t * 200 + oc) * 29 + r)) * 29 + col;
                        out[base] = s ? 1.f : 0.f;
                        out[OUT_HALF + base] = s ? pot : 0.f;
                    }
                }
            }
        }
    }
}

extern "C" void kernel_launch(void* const* d_in, const int* in_sizes, int n_in,
                              void* d_out, int out_size, void* d_ws, size_t ws_size,
                              hipStream_t stream) {
    const float* x  = (const float*)d_in[0];
    const float* w1 = (const float*)d_in[1];
    const float* w2 = (const float*)d_in[2];
    const float* w3 = (const float*)d_in[3];
    float* out = (float*)d_out;

    // workspace layout (bytes):
    //   mask1 u32: [0, 1,024,000)            2 planes x 20*80*80
    //   pool2 u8 : [1,024,000, 4,669,000)    20*250*27*27
    //   w2t  f32 : [4,669,056, +270,000)     270x250  (ends 4,939,056)
    //   pad      : [4,939,056, 4,943,872)    absorbs conv2 stray oc reads
    //   flags2   : [4,943,872, +2,160)       u32[20*27]
    unsigned int* mask1 = (unsigned int*)d_ws;
    unsigned char* pool2 = (unsigned char*)d_ws + 1024000;
    float* w2t = (float*)((char*)d_ws + 4669056);
    unsigned int* flags2 = (unsigned int*)((char*)d_ws + 4943872);

    k_transpose<<<(250 * 270 + 255) / 256, 256, 0, stream>>>(w2, w2t, 250, 270,
                                                             flags2, 540);
    k_conv1<<<20 * 5 * 5 * 2, 256, 0, stream>>>(x, w1, mask1);
    k_conv2<<<20 * 4 * 7 * 27, 256, 0, stream>>>(mask1, w2t, pool2, flags2);
    k_conv3<<<20 * 5 * 15, 320, 0, stream>>>(pool2, w3, out, flags2);
}